// Round 1
// baseline (1125.853 us; speedup 1.0000x reference)
//
#include <hip/hip_runtime.h>
#include <hip/hip_bf16.h>
#include <math.h>

#define N_NODES 50000
#define N_EDGES 800000
#define NFEAT   256
#define NHID    128
#define ZDIM    32
#define N_PAIRS 10000

// ---------------- row_ptr build (adj_row is sorted ascending) ----------------
__global__ void k_build_row_ptr(const int* __restrict__ row, int* __restrict__ row_ptr) {
    int e = blockIdx.x * blockDim.x + threadIdx.x;
    if (e >= N_EDGES) return;
    int cur  = row[e];
    int prev = (e == 0) ? -1 : row[e - 1];
    for (int r = prev + 1; r <= cur; ++r) row_ptr[r] = e;
    if (e == N_EDGES - 1) {
        for (int r = cur + 1; r <= N_NODES; ++r) row_ptr[r] = N_EDGES;
    }
}

// ---------------- dense GEMM: Y[N,128] = X[N,K] @ W[K,128] ----------------
// 128 threads/block, each block does 16 rows. X rows staged in LDS (broadcast
// reads), W columns read coalesced (thread = output column).
template <int K>
__global__ __launch_bounds__(128) void k_gemm(const float* __restrict__ X,
                                              const float* __restrict__ W,
                                              float* __restrict__ Y) {
    const int ROWS = 16;
    __shared__ float xs[ROWS * K];
    const int tid = threadIdx.x;
    const long r0 = (long)blockIdx.x * ROWS;

    for (int i = tid; i < ROWS * K; i += 128) xs[i] = X[r0 * K + i];
    __syncthreads();

    float acc[ROWS];
#pragma unroll
    for (int r = 0; r < ROWS; ++r) acc[r] = 0.f;

    for (int k = 0; k < K; ++k) {
        float wv = W[k * 128 + tid];
#pragma unroll
        for (int r = 0; r < ROWS; ++r) acc[r] += xs[r * K + k] * wv;
    }
#pragma unroll
    for (int r = 0; r < ROWS; ++r) Y[(r0 + r) * 128 + tid] = acc[r];
}

// ---------------- spmm + bias + relu (+ residual), fused ----------------
// one block per destination node, 128 threads = 128 features.
// out may alias res (block r reads only row r of res before writing row r).
template <bool HAS_RES>
__global__ __launch_bounds__(128) void k_spmm_post(const float* __restrict__ H,
                                                   const int* __restrict__ row_ptr,
                                                   const int* __restrict__ col,
                                                   const float* __restrict__ val,
                                                   const float* __restrict__ bias,
                                                   const float* __restrict__ res,
                                                   float* __restrict__ out) {
    const int r = blockIdx.x;
    const int f = threadIdx.x;
    const int e0 = row_ptr[r], e1 = row_ptr[r + 1];
    float acc = 0.f;
    for (int e = e0; e < e1; ++e) {
        float v = val[e];
        int   c = col[e];
        acc += v * H[(long)c * 128 + f];
    }
    acc += bias[f];
    acc = fmaxf(acc, 0.f);
    if (HAS_RES) acc += res[(long)r * 128 + f];
    out[(long)r * 128 + f] = acc;
}

// ---------------- bilinear decode: feat[p,k] = elu(a_p^T W_k b_p + bb_k) -----
// 256 threads/block = 8 pairs x 32 lanes; each lane owns 4 consecutive e cols.
__global__ __launch_bounds__(256) void k_bilinear(const float* __restrict__ latent,
                                                  const int* __restrict__ idx0,
                                                  const int* __restrict__ idx1,
                                                  const float* __restrict__ bw,
                                                  const float* __restrict__ bb,
                                                  float* __restrict__ feat) {
    const int PB = 8;
    __shared__ float as[PB][128];
    __shared__ float bs[PB][128];
    const int p0   = blockIdx.x * PB;
    const int pl   = threadIdx.x >> 5;
    const int lane = threadIdx.x & 31;

    for (int i = threadIdx.x; i < PB * 128; i += 256) {
        int p = i >> 7, d = i & 127;
        as[p][d] = latent[(long)idx0[p0 + p] * 128 + d];
        bs[p][d] = latent[(long)idx1[p0 + p] * 128 + d];
    }
    __syncthreads();

    // hoist this thread's 4 b-values (constant over k)
    const int e0 = lane * 4;
    const float b0 = bs[pl][e0], b1 = bs[pl][e0 + 1], b2 = bs[pl][e0 + 2], b3 = bs[pl][e0 + 3];

    const int p = p0 + pl;
    for (int k = 0; k < ZDIM; ++k) {
        const float4* W4 = reinterpret_cast<const float4*>(bw + (long)k * NHID * NHID);
        float t0 = 0.f, t1 = 0.f, t2 = 0.f, t3 = 0.f;
#pragma unroll 8
        for (int d = 0; d < 128; ++d) {
            float a  = as[pl][d];
            float4 w = W4[d * 32 + lane];
            t0 += a * w.x; t1 += a * w.y; t2 += a * w.z; t3 += a * w.w;
        }
        float partial = t0 * b0 + t1 * b1 + t2 * b2 + t3 * b3;
#pragma unroll
        for (int off = 16; off; off >>= 1) partial += __shfl_down(partial, off, 32);
        if (lane == 0) {
            float v = partial + bb[k];
            feat[(long)p * ZDIM + k] = (v > 0.f) ? v : (expf(v) - 1.f);
        }
    }
}

// ---------------- tiny MLP: pred = elu(feat@dw1+db1) @ dw2 + db2 ----------------
__global__ void k_mlp(const float* __restrict__ feat,
                      const float* __restrict__ dw1, const float* __restrict__ db1,
                      const float* __restrict__ dw2, const float* __restrict__ db2,
                      float* __restrict__ pred) {
    int p = blockIdx.x * blockDim.x + threadIdx.x;
    if (p >= N_PAIRS) return;
    float f[ZDIM];
#pragma unroll
    for (int k = 0; k < ZDIM; ++k) f[k] = feat[(long)p * ZDIM + k];
    float acc = db2[0];
    for (int j = 0; j < ZDIM; ++j) {
        float h = db1[j];
#pragma unroll
        for (int k = 0; k < ZDIM; ++k) h += f[k] * dw1[k * ZDIM + j];
        h = (h > 0.f) ? h : (expf(h) - 1.f);
        acc += h * dw2[j];
    }
    pred[p] = acc;
}

extern "C" void kernel_launch(void* const* d_in, const int* in_sizes, int n_in,
                              void* d_out, int out_size, void* d_ws, size_t ws_size,
                              hipStream_t stream) {
    const float* features = (const float*)d_in[0];
    const int*   adj_row  = (const int*)d_in[1];
    const int*   adj_col  = (const int*)d_in[2];
    const float* adj_val  = (const float*)d_in[3];
    const int*   idx      = (const int*)d_in[4];   // [2, N_PAIRS]
    const float* W0 = (const float*)d_in[5];
    const float* b0 = (const float*)d_in[6];
    const float* W1 = (const float*)d_in[7];
    const float* b1 = (const float*)d_in[8];
    const float* W2 = (const float*)d_in[9];
    const float* b2 = (const float*)d_in[10];
    const float* bil_w = (const float*)d_in[11];
    const float* bil_b = (const float*)d_in[12];
    const float* dw1 = (const float*)d_in[13];
    const float* db1 = (const float*)d_in[14];
    const float* dw2 = (const float*)d_in[15];
    const float* db2 = (const float*)d_in[16];

    float* pred   = (float*)d_out;                // [N_PAIRS]
    float* latent = (float*)d_out + N_PAIRS;      // [N_NODES,128]

    // workspace carve-up
    char* ws = (char*)d_ws;
    float* xw   = (float*)ws;                                 ws += (size_t)N_NODES * NHID * 4;
    float* xcur = (float*)ws;                                 ws += (size_t)N_NODES * NHID * 4;
    int*   row_ptr = (int*)ws;                                ws += (size_t)(N_NODES + 1) * 4;
    float* feat = (float*)ws;                                 ws += (size_t)N_PAIRS * ZDIM * 4;

    const int*  idx0 = idx;
    const int*  idx1 = idx + N_PAIRS;

    // CSR row pointers from sorted COO rows
    k_build_row_ptr<<<(N_EDGES + 255) / 256, 256, 0, stream>>>(adj_row, row_ptr);

    const int GB = N_NODES / 16;   // 3125 blocks

    // layer 0: x = relu(A @ (F @ W0) + b0)
    k_gemm<NFEAT><<<GB, 128, 0, stream>>>(features, W0, xw);
    k_spmm_post<false><<<N_NODES, 128, 0, stream>>>(xw, row_ptr, adj_col, adj_val, b0, nullptr, xcur);

    // layer 1: x = relu(A @ (x @ W1) + b1) + x   (in-place residual)
    k_gemm<NHID><<<GB, 128, 0, stream>>>(xcur, W1, xw);
    k_spmm_post<true><<<N_NODES, 128, 0, stream>>>(xw, row_ptr, adj_col, adj_val, b1, xcur, xcur);

    // layer 2: latent = relu(A @ (x @ W2) + b2) + x   (written to d_out)
    k_gemm<NHID><<<GB, 128, 0, stream>>>(xcur, W2, xw);
    k_spmm_post<true><<<N_NODES, 128, 0, stream>>>(xw, row_ptr, adj_col, adj_val, b2, xcur, latent);

    // decode
    k_bilinear<<<N_PAIRS / 8, 256, 0, stream>>>(latent, idx0, idx1, bil_w, bil_b, feat);
    k_mlp<<<(N_PAIRS + 127) / 128, 128, 0, stream>>>(feat, dw1, db1, dw2, db2, pred);
}

// Round 2
// 762.879 us; speedup vs baseline: 1.4758x; 1.4758x over previous
//
#include <hip/hip_runtime.h>
#include <hip/hip_bf16.h>
#include <math.h>

#define N_NODES 50000
#define N_EDGES 800000
#define NFEAT   256
#define NHID    128
#define ZDIM    32
#define N_PAIRS 10000

// ---------------- row_ptr build (adj_row is sorted ascending) ----------------
__global__ void k_build_row_ptr(const int* __restrict__ row, int* __restrict__ row_ptr) {
    int e = blockIdx.x * blockDim.x + threadIdx.x;
    if (e >= N_EDGES) return;
    int cur  = row[e];
    int prev = (e == 0) ? -1 : row[e - 1];
    for (int r = prev + 1; r <= cur; ++r) row_ptr[r] = e;
    if (e == N_EDGES - 1) {
        for (int r = cur + 1; r <= N_NODES; ++r) row_ptr[r] = N_EDGES;
    }
}

// ---------------- dense GEMM: Y[N,128] = X[N,K] @ W[K,128] ----------------
// 256 threads/block, 32 rows/block. Thread = (row-half rh of 8 rows, col-pair cp).
// X tile staged in LDS; per 4-k step: 4 float2 W loads + 8 b128 LDS broadcast
// reads + 64 FMAs -> FMA-pipe bound.
template <int K>
__global__ __launch_bounds__(256) void k_gemm(const float* __restrict__ X,
                                              const float* __restrict__ W,
                                              float* __restrict__ Y) {
    const int ROWS = 32;
    __shared__ float xs[ROWS][K];
    const int tid = threadIdx.x;
    const long r0 = (long)blockIdx.x * ROWS;

    // stage X tile (guard rows >= N_NODES)
    const float4* X4 = reinterpret_cast<const float4*>(X + r0 * K);
    float4* xs4 = reinterpret_cast<float4*>(&xs[0][0]);
    const int NV = ROWS * K / 4;
    for (int i = tid; i < NV; i += 256) {
        int row = i / (K / 4);
        float4 v = make_float4(0.f, 0.f, 0.f, 0.f);
        if (r0 + row < N_NODES) v = X4[i];
        xs4[i] = v;
    }
    __syncthreads();

    const int cp = tid & 63;        // cols 2*cp, 2*cp+1
    const int rbase = (tid >> 6) * 8;

    float acc[8][2];
#pragma unroll
    for (int r = 0; r < 8; ++r) { acc[r][0] = 0.f; acc[r][1] = 0.f; }

    for (int k = 0; k < K; k += 4) {
        float2 w0 = *reinterpret_cast<const float2*>(&W[(k + 0) * 128 + 2 * cp]);
        float2 w1 = *reinterpret_cast<const float2*>(&W[(k + 1) * 128 + 2 * cp]);
        float2 w2 = *reinterpret_cast<const float2*>(&W[(k + 2) * 128 + 2 * cp]);
        float2 w3 = *reinterpret_cast<const float2*>(&W[(k + 3) * 128 + 2 * cp]);
#pragma unroll
        for (int r = 0; r < 8; ++r) {
            float4 a = *reinterpret_cast<const float4*>(&xs[rbase + r][k]);
            acc[r][0] += a.x * w0.x + a.y * w1.x + a.z * w2.x + a.w * w3.x;
            acc[r][1] += a.x * w0.y + a.y * w1.y + a.z * w2.y + a.w * w3.y;
        }
    }
#pragma unroll
    for (int r = 0; r < 8; ++r) {
        long row = r0 + rbase + r;
        if (row < N_NODES)
            *reinterpret_cast<float2*>(&Y[row * 128 + 2 * cp]) = make_float2(acc[r][0], acc[r][1]);
    }
}

// ---------------- spmm + bias + relu (+ residual), fused ----------------
template <bool HAS_RES>
__global__ __launch_bounds__(128) void k_spmm_post(const float* __restrict__ H,
                                                   const int* __restrict__ row_ptr,
                                                   const int* __restrict__ col,
                                                   const float* __restrict__ val,
                                                   const float* __restrict__ bias,
                                                   const float* __restrict__ res,
                                                   float* __restrict__ out) {
    const int r = blockIdx.x;
    const int f = threadIdx.x;
    const int e0 = row_ptr[r], e1 = row_ptr[r + 1];
    float acc = 0.f;
    for (int e = e0; e < e1; ++e) {
        float v = val[e];
        int   c = col[e];
        acc += v * H[(long)c * 128 + f];
    }
    acc += bias[f];
    acc = fmaxf(acc, 0.f);
    if (HAS_RES) acc += res[(long)r * 128 + f];
    out[(long)r * 128 + f] = acc;
}

// ---------------- bilinear decode: feat[p,k] = elu(a_p^T W_k b_p + bb_k) -----
// 32 pairs/block staged in LDS, 8 k-slices/block, grid (313, 4).
// 256 threads = 8 groups x 32 lanes; group owns 4 pairs; lane owns 4 e-cols.
// Per 4-d: 4 global float4 W loads + 4 LDS b128 broadcast reads + 64 FMAs.
#define PB  32
#define KPB 8
__global__ __launch_bounds__(256) void k_bilinear(const float* __restrict__ latent,
                                                  const int* __restrict__ idx0,
                                                  const int* __restrict__ idx1,
                                                  const float* __restrict__ bw,
                                                  const float* __restrict__ bb,
                                                  float* __restrict__ feat) {
    __shared__ float as[PB][128];
    __shared__ float bs[PB][128];
    const int p0   = blockIdx.x * PB;
    const int kb   = blockIdx.y * KPB;
    const int g    = threadIdx.x >> 5;      // group 0..7
    const int lane = threadIdx.x & 31;

    // stage a/b rows (clamp OOB pairs to 0 for the load; stores are guarded)
    const float4* L4 = reinterpret_cast<const float4*>(latent);
    for (int i = threadIdx.x; i < PB * 32; i += 256) {
        int p = i >> 5, q = i & 31;
        int pi = p0 + p; if (pi >= N_PAIRS) pi = N_PAIRS - 1;
        reinterpret_cast<float4*>(&as[p][0])[q] = L4[(long)idx0[pi] * 32 + q];
        reinterpret_cast<float4*>(&bs[p][0])[q] = L4[(long)idx1[pi] * 32 + q];
    }
    __syncthreads();

    const int pbase = g * 4;   // 4 pairs per group

    for (int kk = 0; kk < KPB; ++kk) {
        const int kidx = kb + kk;
        const float4* W4 = reinterpret_cast<const float4*>(bw + (long)kidx * NHID * NHID);

        float acc[4][4];
#pragma unroll
        for (int pp = 0; pp < 4; ++pp)
#pragma unroll
            for (int e = 0; e < 4; ++e) acc[pp][e] = 0.f;

        for (int d = 0; d < 128; d += 4) {
            float4 w0 = W4[(d + 0) * 32 + lane];
            float4 w1 = W4[(d + 1) * 32 + lane];
            float4 w2 = W4[(d + 2) * 32 + lane];
            float4 w3 = W4[(d + 3) * 32 + lane];
#pragma unroll
            for (int pp = 0; pp < 4; ++pp) {
                float4 a = *reinterpret_cast<const float4*>(&as[pbase + pp][d]);
                acc[pp][0] += a.x * w0.x + a.y * w1.x + a.z * w2.x + a.w * w3.x;
                acc[pp][1] += a.x * w0.y + a.y * w1.y + a.z * w2.y + a.w * w3.y;
                acc[pp][2] += a.x * w0.z + a.y * w1.z + a.z * w2.z + a.w * w3.z;
                acc[pp][3] += a.x * w0.w + a.y * w1.w + a.z * w2.w + a.w * w3.w;
            }
        }

        const float bbk = bb[kidx];
#pragma unroll
        for (int pp = 0; pp < 4; ++pp) {
            float4 bv = *reinterpret_cast<const float4*>(&bs[pbase + pp][lane * 4]);
            float partial = acc[pp][0] * bv.x + acc[pp][1] * bv.y +
                            acc[pp][2] * bv.z + acc[pp][3] * bv.w;
#pragma unroll
            for (int off = 16; off; off >>= 1) partial += __shfl_down(partial, off, 32);
            if (lane == 0) {
                int p = p0 + pbase + pp;
                if (p < N_PAIRS) {
                    float v = partial + bbk;
                    feat[(long)p * ZDIM + kidx] = (v > 0.f) ? v : (expf(v) - 1.f);
                }
            }
        }
    }
}

// ---------------- tiny MLP ----------------
__global__ void k_mlp(const float* __restrict__ feat,
                      const float* __restrict__ dw1, const float* __restrict__ db1,
                      const float* __restrict__ dw2, const float* __restrict__ db2,
                      float* __restrict__ pred) {
    int p = blockIdx.x * blockDim.x + threadIdx.x;
    if (p >= N_PAIRS) return;
    float f[ZDIM];
#pragma unroll
    for (int k = 0; k < ZDIM; ++k) f[k] = feat[(long)p * ZDIM + k];
    float acc = db2[0];
    for (int j = 0; j < ZDIM; ++j) {
        float h = db1[j];
#pragma unroll
        for (int k = 0; k < ZDIM; ++k) h += f[k] * dw1[k * ZDIM + j];
        h = (h > 0.f) ? h : (expf(h) - 1.f);
        acc += h * dw2[j];
    }
    pred[p] = acc;
}

extern "C" void kernel_launch(void* const* d_in, const int* in_sizes, int n_in,
                              void* d_out, int out_size, void* d_ws, size_t ws_size,
                              hipStream_t stream) {
    const float* features = (const float*)d_in[0];
    const int*   adj_row  = (const int*)d_in[1];
    const int*   adj_col  = (const int*)d_in[2];
    const float* adj_val  = (const float*)d_in[3];
    const int*   idx      = (const int*)d_in[4];   // [2, N_PAIRS]
    const float* W0 = (const float*)d_in[5];
    const float* b0 = (const float*)d_in[6];
    const float* W1 = (const float*)d_in[7];
    const float* b1 = (const float*)d_in[8];
    const float* W2 = (const float*)d_in[9];
    const float* b2 = (const float*)d_in[10];
    const float* bil_w = (const float*)d_in[11];
    const float* bil_b = (const float*)d_in[12];
    const float* dw1 = (const float*)d_in[13];
    const float* db1 = (const float*)d_in[14];
    const float* dw2 = (const float*)d_in[15];
    const float* db2 = (const float*)d_in[16];

    float* pred   = (float*)d_out;                // [N_PAIRS]
    float* latent = (float*)d_out + N_PAIRS;      // [N_NODES,128]

    // workspace carve-up
    char* ws = (char*)d_ws;
    float* xw   = (float*)ws;                                 ws += (size_t)N_NODES * NHID * 4;
    float* xcur = (float*)ws;                                 ws += (size_t)N_NODES * NHID * 4;
    int*   row_ptr = (int*)ws;                                ws += (size_t)(N_NODES + 1) * 4;
    float* feat = (float*)ws;                                 ws += (size_t)N_PAIRS * ZDIM * 4;

    const int*  idx0 = idx;
    const int*  idx1 = idx + N_PAIRS;

    k_build_row_ptr<<<(N_EDGES + 255) / 256, 256, 0, stream>>>(adj_row, row_ptr);

    const int GB = (N_NODES + 31) / 32;   // 1563 blocks

    // layer 0
    k_gemm<NFEAT><<<GB, 256, 0, stream>>>(features, W0, xw);
    k_spmm_post<false><<<N_NODES, 128, 0, stream>>>(xw, row_ptr, adj_col, adj_val, b0, nullptr, xcur);

    // layer 1 (in-place residual)
    k_gemm<NHID><<<GB, 256, 0, stream>>>(xcur, W1, xw);
    k_spmm_post<true><<<N_NODES, 128, 0, stream>>>(xw, row_ptr, adj_col, adj_val, b1, xcur, xcur);

    // layer 2 -> latent in d_out
    k_gemm<NHID><<<GB, 256, 0, stream>>>(xcur, W2, xw);
    k_spmm_post<true><<<N_NODES, 128, 0, stream>>>(xw, row_ptr, adj_col, adj_val, b2, xcur, latent);

    // decode
    dim3 bgrid((N_PAIRS + PB - 1) / PB, ZDIM / KPB);
    k_bilinear<<<bgrid, 256, 0, stream>>>(latent, idx0, idx1, bil_w, bil_b, feat);
    k_mlp<<<(N_PAIRS + 127) / 128, 128, 0, stream>>>(feat, dw1, db1, dw2, db2, pred);
}

// Round 3
// 688.886 us; speedup vs baseline: 1.6343x; 1.1074x over previous
//
#include <hip/hip_runtime.h>
#include <hip/hip_bf16.h>
#include <math.h>

#define N_NODES 50000
#define N_EDGES 800000
#define NFEAT   256
#define NHID    128
#define ZDIM    32
#define N_PAIRS 10000

typedef __attribute__((ext_vector_type(8))) short bf16x8;
typedef __attribute__((ext_vector_type(4))) float f32x4;

// ---------------- row_ptr build (adj_row is sorted ascending) ----------------
__global__ void k_build_row_ptr(const int* __restrict__ row, int* __restrict__ row_ptr) {
    int e = blockIdx.x * blockDim.x + threadIdx.x;
    if (e >= N_EDGES) return;
    int cur  = row[e];
    int prev = (e == 0) ? -1 : row[e - 1];
    for (int r = prev + 1; r <= cur; ++r) row_ptr[r] = e;
    if (e == N_EDGES - 1) {
        for (int r = cur + 1; r <= N_NODES; ++r) row_ptr[r] = N_EDGES;
    }
}

// ---------------- dense GEMM: Y[N,128] = X[N,K] @ W[K,128] (fp32) ----------------
template <int K>
__global__ __launch_bounds__(256) void k_gemm(const float* __restrict__ X,
                                              const float* __restrict__ W,
                                              float* __restrict__ Y) {
    const int ROWS = 32;
    __shared__ float xs[ROWS][K];
    const int tid = threadIdx.x;
    const long r0 = (long)blockIdx.x * ROWS;

    const float4* X4 = reinterpret_cast<const float4*>(X + r0 * K);
    float4* xs4 = reinterpret_cast<float4*>(&xs[0][0]);
    const int NV = ROWS * K / 4;
    for (int i = tid; i < NV; i += 256) {
        int row = i / (K / 4);
        float4 v = make_float4(0.f, 0.f, 0.f, 0.f);
        if (r0 + row < N_NODES) v = X4[i];
        xs4[i] = v;
    }
    __syncthreads();

    const int cp = tid & 63;
    const int rbase = (tid >> 6) * 8;

    float acc[8][2];
#pragma unroll
    for (int r = 0; r < 8; ++r) { acc[r][0] = 0.f; acc[r][1] = 0.f; }

    for (int k = 0; k < K; k += 4) {
        float2 w0 = *reinterpret_cast<const float2*>(&W[(k + 0) * 128 + 2 * cp]);
        float2 w1 = *reinterpret_cast<const float2*>(&W[(k + 1) * 128 + 2 * cp]);
        float2 w2 = *reinterpret_cast<const float2*>(&W[(k + 2) * 128 + 2 * cp]);
        float2 w3 = *reinterpret_cast<const float2*>(&W[(k + 3) * 128 + 2 * cp]);
#pragma unroll
        for (int r = 0; r < 8; ++r) {
            float4 a = *reinterpret_cast<const float4*>(&xs[rbase + r][k]);
            acc[r][0] += a.x * w0.x + a.y * w1.x + a.z * w2.x + a.w * w3.x;
            acc[r][1] += a.x * w0.y + a.y * w1.y + a.z * w2.y + a.w * w3.y;
        }
    }
#pragma unroll
    for (int r = 0; r < 8; ++r) {
        long row = r0 + rbase + r;
        if (row < N_NODES)
            *reinterpret_cast<float2*>(&Y[row * 128 + 2 * cp]) = make_float2(acc[r][0], acc[r][1]);
    }
}

// ---------------- spmm + bias + relu (+ residual), fused ----------------
template <bool HAS_RES>
__global__ __launch_bounds__(128) void k_spmm_post(const float* __restrict__ H,
                                                   const int* __restrict__ row_ptr,
                                                   const int* __restrict__ col,
                                                   const float* __restrict__ val,
                                                   const float* __restrict__ bias,
                                                   const float* __restrict__ res,
                                                   float* __restrict__ out) {
    const int r = blockIdx.x;
    const int f = threadIdx.x;
    const int e0 = row_ptr[r], e1 = row_ptr[r + 1];
    float acc = 0.f;
    for (int e = e0; e < e1; ++e) {
        float v = val[e];
        int   c = col[e];
        acc += v * H[(long)c * 128 + f];
    }
    acc += bias[f];
    acc = fmaxf(acc, 0.f);
    if (HAS_RES) acc += res[(long)r * 128 + f];
    out[(long)r * 128 + f] = acc;
}

// ---------------- pack bil_w into MFMA B-fragment order, f32 -> bf16 ----------
// chunk c = (k*4+kk)*8+n holds 512 bf16; element (lane,j) = W[k][kk*32+(l>>4)*8+j][n*16+(l&15)]
__global__ __launch_bounds__(256) void k_pack_w(const float* __restrict__ bw,
                                                __hip_bfloat16* __restrict__ wpk) {
    int i  = blockIdx.x * 256 + threadIdx.x;     // 0 .. 2^19-1
    int j  = i & 7;
    int l  = (i >> 3) & 63;
    int n  = (i >> 9) & 7;
    int kk = (i >> 12) & 3;
    int k  = i >> 14;
    int d  = kk * 32 + (l >> 4) * 8 + j;
    int e  = n * 16 + (l & 15);
    wpk[i] = __float2bfloat16(bw[((long)k * 128 + d) * 128 + e]);
}

// ---------------- bilinear decode via MFMA ----------------
// block = 1024 threads (16 waves), 32 pairs. wave w owns k = 2w, 2w+1.
// Per wave: A frags (2 M-tiles x 4 kk) hoisted from LDS; per (n,k): 4 coalesced
// W-frag global loads + 8 mfma; contract C with b from LDS; xor-reduce over 16
// lanes; fused bias+ELU write of feat.
__global__ __launch_bounds__(1024) void k_bilinear_mfma(const float* __restrict__ latent,
                                                        const int* __restrict__ idx0,
                                                        const int* __restrict__ idx1,
                                                        const __hip_bfloat16* __restrict__ wpk,
                                                        const float* __restrict__ bb,
                                                        float* __restrict__ feat) {
    __shared__ __hip_bfloat16 as[32][136];   // bf16 a-rows, padded (2-way conflicts max)
    __shared__ float          bs[32][132];   // f32 b-rows for contraction
    const int p0  = blockIdx.x * 32;
    const int tid = threadIdx.x;

    // stage: thread t -> pair p = t>>5, quad q = t&31 (4 floats)
    {
        int p = tid >> 5, q = tid & 31;
        int pi = p0 + p; if (pi >= N_PAIRS) pi = N_PAIRS - 1;
        const float4 av = *reinterpret_cast<const float4*>(&latent[(long)idx0[pi] * 128 + q * 4]);
        const float4 bv = *reinterpret_cast<const float4*>(&latent[(long)idx1[pi] * 128 + q * 4]);
        as[p][q * 4 + 0] = __float2bfloat16(av.x);
        as[p][q * 4 + 1] = __float2bfloat16(av.y);
        as[p][q * 4 + 2] = __float2bfloat16(av.z);
        as[p][q * 4 + 3] = __float2bfloat16(av.w);
        *reinterpret_cast<float4*>(&bs[p][q * 4]) = bv;
    }
    __syncthreads();

    const int wave = tid >> 6;          // 0..15  -> k = 2*wave + k2
    const int lane = tid & 63;
    const int l15  = lane & 15, l4 = lane >> 4;

    // hoist A fragments: af[M][kk], lane l holds A[M*16 + (l&15)][kk*32 + (l>>4)*8 + j]
    bf16x8 af[2][4];
#pragma unroll
    for (int M = 0; M < 2; ++M)
#pragma unroll
        for (int kk = 0; kk < 4; ++kk)
            af[M][kk] = *reinterpret_cast<const bf16x8*>(&as[M * 16 + l15][kk * 32 + l4 * 8]);

    float fsum[2][2][4];
#pragma unroll
    for (int M = 0; M < 2; ++M)
#pragma unroll
        for (int k2 = 0; k2 < 2; ++k2)
#pragma unroll
            for (int q = 0; q < 4; ++q) fsum[M][k2][q] = 0.f;

    for (int n = 0; n < 8; ++n) {
        float bval[2][4];   // b[M*16 + l4*4 + q][n*16 + l15]
#pragma unroll
        for (int M = 0; M < 2; ++M)
#pragma unroll
            for (int q = 0; q < 4; ++q)
                bval[M][q] = bs[M * 16 + l4 * 4 + q][n * 16 + l15];

#pragma unroll
        for (int k2 = 0; k2 < 2; ++k2) {
            const int k = wave * 2 + k2;
            f32x4 acc0 = {0.f, 0.f, 0.f, 0.f};
            f32x4 acc1 = {0.f, 0.f, 0.f, 0.f};
#pragma unroll
            for (int kk = 0; kk < 4; ++kk) {
                bf16x8 wf = *reinterpret_cast<const bf16x8*>(
                    &wpk[(((long)(k * 4 + kk) * 8 + n) * 512) + lane * 8]);
                acc0 = __builtin_amdgcn_mfma_f32_16x16x32_bf16(af[0][kk], wf, acc0, 0, 0, 0);
                acc1 = __builtin_amdgcn_mfma_f32_16x16x32_bf16(af[1][kk], wf, acc1, 0, 0, 0);
            }
#pragma unroll
            for (int q = 0; q < 4; ++q) {
                fsum[0][k2][q] += acc0[q] * bval[0][q];
                fsum[1][k2][q] += acc1[q] * bval[1][q];
            }
        }
    }

    // reduce over the 16 e-lanes in each group; write feat with bias+ELU
#pragma unroll
    for (int M = 0; M < 2; ++M)
#pragma unroll
        for (int k2 = 0; k2 < 2; ++k2) {
            float v0 = fsum[M][k2][0], v1 = fsum[M][k2][1],
                  v2 = fsum[M][k2][2], v3 = fsum[M][k2][3];
#pragma unroll
            for (int off = 1; off < 16; off <<= 1) {
                v0 += __shfl_xor(v0, off);
                v1 += __shfl_xor(v1, off);
                v2 += __shfl_xor(v2, off);
                v3 += __shfl_xor(v3, off);
            }
            if (l15 == 0) {
                const int k = wave * 2 + k2;
                const float bbk = bb[k];
                float vv[4] = {v0, v1, v2, v3};
#pragma unroll
                for (int q = 0; q < 4; ++q) {
                    int p = p0 + M * 16 + l4 * 4 + q;
                    if (p < N_PAIRS) {
                        float v = vv[q] + bbk;
                        feat[(long)p * ZDIM + k] = (v > 0.f) ? v : (expf(v) - 1.f);
                    }
                }
            }
        }
}

// ---------------- tiny MLP ----------------
__global__ void k_mlp(const float* __restrict__ feat,
                      const float* __restrict__ dw1, const float* __restrict__ db1,
                      const float* __restrict__ dw2, const float* __restrict__ db2,
                      float* __restrict__ pred) {
    int p = blockIdx.x * blockDim.x + threadIdx.x;
    if (p >= N_PAIRS) return;
    float f[ZDIM];
#pragma unroll
    for (int k = 0; k < ZDIM; ++k) f[k] = feat[(long)p * ZDIM + k];
    float acc = db2[0];
    for (int j = 0; j < ZDIM; ++j) {
        float h = db1[j];
#pragma unroll
        for (int k = 0; k < ZDIM; ++k) h += f[k] * dw1[k * ZDIM + j];
        h = (h > 0.f) ? h : (expf(h) - 1.f);
        acc += h * dw2[j];
    }
    pred[p] = acc;
}

extern "C" void kernel_launch(void* const* d_in, const int* in_sizes, int n_in,
                              void* d_out, int out_size, void* d_ws, size_t ws_size,
                              hipStream_t stream) {
    const float* features = (const float*)d_in[0];
    const int*   adj_row  = (const int*)d_in[1];
    const int*   adj_col  = (const int*)d_in[2];
    const float* adj_val  = (const float*)d_in[3];
    const int*   idx      = (const int*)d_in[4];   // [2, N_PAIRS]
    const float* W0 = (const float*)d_in[5];
    const float* b0 = (const float*)d_in[6];
    const float* W1 = (const float*)d_in[7];
    const float* b1 = (const float*)d_in[8];
    const float* W2 = (const float*)d_in[9];
    const float* b2 = (const float*)d_in[10];
    const float* bil_w = (const float*)d_in[11];
    const float* bil_b = (const float*)d_in[12];
    const float* dw1 = (const float*)d_in[13];
    const float* db1 = (const float*)d_in[14];
    const float* dw2 = (const float*)d_in[15];
    const float* db2 = (const float*)d_in[16];

    float* pred   = (float*)d_out;                // [N_PAIRS]
    float* latent = (float*)d_out + N_PAIRS;      // [N_NODES,128]

    // workspace carve-up
    char* ws = (char*)d_ws;
    float* xw   = (float*)ws;                                 ws += (size_t)N_NODES * NHID * 4;
    float* xcur = (float*)ws;                                 ws += (size_t)N_NODES * NHID * 4;
    int*   row_ptr = (int*)ws;                                ws += (size_t)(N_NODES + 1) * 4;
    float* feat = (float*)ws;                                 ws += (size_t)N_PAIRS * ZDIM * 4;
    __hip_bfloat16* wpk = (__hip_bfloat16*)ws;                ws += (size_t)ZDIM * NHID * NHID * 2;

    const int*  idx0 = idx;
    const int*  idx1 = idx + N_PAIRS;

    k_build_row_ptr<<<(N_EDGES + 255) / 256, 256, 0, stream>>>(adj_row, row_ptr);
    k_pack_w<<<(ZDIM * NHID * NHID) / 256, 256, 0, stream>>>(bil_w, wpk);

    const int GB = (N_NODES + 31) / 32;   // 1563 blocks

    // layer 0
    k_gemm<NFEAT><<<GB, 256, 0, stream>>>(features, W0, xw);
    k_spmm_post<false><<<N_NODES, 128, 0, stream>>>(xw, row_ptr, adj_col, adj_val, b0, nullptr, xcur);

    // layer 1 (in-place residual)
    k_gemm<NHID><<<GB, 256, 0, stream>>>(xcur, W1, xw);
    k_spmm_post<true><<<N_NODES, 128, 0, stream>>>(xw, row_ptr, adj_col, adj_val, b1, xcur, xcur);

    // layer 2 -> latent in d_out
    k_gemm<NHID><<<GB, 256, 0, stream>>>(xcur, W2, xw);
    k_spmm_post<true><<<N_NODES, 128, 0, stream>>>(xw, row_ptr, adj_col, adj_val, b2, xcur, latent);

    // decode
    k_bilinear_mfma<<<(N_PAIRS + 31) / 32, 1024, 0, stream>>>(latent, idx0, idx1, wpk, bil_b, feat);
    k_mlp<<<(N_PAIRS + 127) / 128, 128, 0, stream>>>(feat, dw1, db1, dw2, db2, pred);
}

// Round 4
// 563.268 us; speedup vs baseline: 1.9988x; 1.2230x over previous
//
#include <hip/hip_runtime.h>
#include <hip/hip_bf16.h>
#include <math.h>

#define N_NODES 50000
#define N_EDGES 800000
#define NFEAT   256
#define NHID    128
#define ZDIM    32
#define N_PAIRS 10000

typedef __attribute__((ext_vector_type(8))) short bf16x8;
typedef __attribute__((ext_vector_type(4))) float f32x4;

// ---------------- row_ptr build (adj_row is sorted ascending) ----------------
__global__ void k_build_row_ptr(const int* __restrict__ row, int* __restrict__ row_ptr) {
    int e = blockIdx.x * blockDim.x + threadIdx.x;
    if (e >= N_EDGES) return;
    int cur  = row[e];
    int prev = (e == 0) ? -1 : row[e - 1];
    for (int r = prev + 1; r <= cur; ++r) row_ptr[r] = e;
    if (e == N_EDGES - 1) {
        for (int r = cur + 1; r <= N_NODES; ++r) row_ptr[r] = N_EDGES;
    }
}

// ---------------- dense GEMM: Y[N,128] = X[N,K] @ W[K,128] (fp32) ----------------
template <int K>
__global__ __launch_bounds__(256) void k_gemm(const float* __restrict__ X,
                                              const float* __restrict__ W,
                                              float* __restrict__ Y) {
    const int ROWS = 32;
    __shared__ float xs[ROWS][K];
    const int tid = threadIdx.x;
    const long r0 = (long)blockIdx.x * ROWS;

    const float4* X4 = reinterpret_cast<const float4*>(X + r0 * K);
    float4* xs4 = reinterpret_cast<float4*>(&xs[0][0]);
    const int NV = ROWS * K / 4;
    for (int i = tid; i < NV; i += 256) {
        int row = i / (K / 4);
        float4 v = make_float4(0.f, 0.f, 0.f, 0.f);
        if (r0 + row < N_NODES) v = X4[i];
        xs4[i] = v;
    }
    __syncthreads();

    const int cp = tid & 63;
    const int rbase = (tid >> 6) * 8;

    float acc[8][2];
#pragma unroll
    for (int r = 0; r < 8; ++r) { acc[r][0] = 0.f; acc[r][1] = 0.f; }

    for (int k = 0; k < K; k += 4) {
        float2 w0 = *reinterpret_cast<const float2*>(&W[(k + 0) * 128 + 2 * cp]);
        float2 w1 = *reinterpret_cast<const float2*>(&W[(k + 1) * 128 + 2 * cp]);
        float2 w2 = *reinterpret_cast<const float2*>(&W[(k + 2) * 128 + 2 * cp]);
        float2 w3 = *reinterpret_cast<const float2*>(&W[(k + 3) * 128 + 2 * cp]);
#pragma unroll
        for (int r = 0; r < 8; ++r) {
            float4 a = *reinterpret_cast<const float4*>(&xs[rbase + r][k]);
            acc[r][0] += a.x * w0.x + a.y * w1.x + a.z * w2.x + a.w * w3.x;
            acc[r][1] += a.x * w0.y + a.y * w1.y + a.z * w2.y + a.w * w3.y;
        }
    }
#pragma unroll
    for (int r = 0; r < 8; ++r) {
        long row = r0 + rbase + r;
        if (row < N_NODES)
            *reinterpret_cast<float2*>(&Y[row * 128 + 2 * cp]) = make_float2(acc[r][0], acc[r][1]);
    }
}

// ---------------- spmm + bias + relu (+ residual), fused, float4 ----------------
// 256 threads = 8 groups x 32 lanes; group = one destination node; lane owns 4 feats.
template <bool HAS_RES>
__global__ __launch_bounds__(256) void k_spmm_post(const float* __restrict__ H,
                                                   const int* __restrict__ row_ptr,
                                                   const int* __restrict__ col,
                                                   const float* __restrict__ val,
                                                   const float* __restrict__ bias,
                                                   const float* __restrict__ res,
                                                   float* __restrict__ out) {
    const int g    = threadIdx.x >> 5;
    const int lane = threadIdx.x & 31;
    const int r    = blockIdx.x * 8 + g;
    if (r >= N_NODES) return;
    const int e0 = row_ptr[r], e1 = row_ptr[r + 1];
    const float4* H4 = reinterpret_cast<const float4*>(H);

    float4 acc = make_float4(0.f, 0.f, 0.f, 0.f);
    int e = e0;
    for (; e + 1 < e1; e += 2) {
        float v0 = val[e];     int c0 = col[e];
        float v1 = val[e + 1]; int c1 = col[e + 1];
        float4 h0 = H4[(long)c0 * 32 + lane];
        float4 h1 = H4[(long)c1 * 32 + lane];
        acc.x += v0 * h0.x + v1 * h1.x;
        acc.y += v0 * h0.y + v1 * h1.y;
        acc.z += v0 * h0.z + v1 * h1.z;
        acc.w += v0 * h0.w + v1 * h1.w;
    }
    if (e < e1) {
        float v0 = val[e]; int c0 = col[e];
        float4 h0 = H4[(long)c0 * 32 + lane];
        acc.x += v0 * h0.x; acc.y += v0 * h0.y; acc.z += v0 * h0.z; acc.w += v0 * h0.w;
    }

    float4 bv = reinterpret_cast<const float4*>(bias)[lane];
    acc.x = fmaxf(acc.x + bv.x, 0.f);
    acc.y = fmaxf(acc.y + bv.y, 0.f);
    acc.z = fmaxf(acc.z + bv.z, 0.f);
    acc.w = fmaxf(acc.w + bv.w, 0.f);
    if (HAS_RES) {
        float4 rv = reinterpret_cast<const float4*>(res)[(long)r * 32 + lane];
        acc.x += rv.x; acc.y += rv.y; acc.z += rv.z; acc.w += rv.w;
    }
    reinterpret_cast<float4*>(out)[(long)r * 32 + lane] = acc;
}

// ---------------- pack bil_w into MFMA B-fragment order, f32 -> bf16 ----------
// chunk c = (k*4+kk)*8+n holds 512 bf16; element (lane,j) = W[k][kk*32+(l>>4)*8+j][n*16+(l&15)]
__global__ __launch_bounds__(256) void k_pack_w(const float* __restrict__ bw,
                                                __hip_bfloat16* __restrict__ wpk) {
    int i  = blockIdx.x * 256 + threadIdx.x;     // 0 .. 2^19-1
    int j  = i & 7;
    int l  = (i >> 3) & 63;
    int n  = (i >> 9) & 7;
    int kk = (i >> 12) & 3;
    int k  = i >> 14;
    int d  = kk * 32 + (l >> 4) * 8 + j;
    int e  = n * 16 + (l & 15);
    wpk[i] = __float2bfloat16(bw[((long)k * 128 + d) * 128 + e]);
}

// ---------------- bilinear decode via MFMA + fused MLP ----------------
// block = 512 threads (8 waves), 32 pairs. wave w owns k = 4w..4w+3.
// fl[k][p] (transposed) holds elu(feat) in LDS; wave 0 then runs the tiny MLP.
__global__ __launch_bounds__(512) void k_bilinear_mfma(const float* __restrict__ latent,
                                                       const int* __restrict__ idx0,
                                                       const int* __restrict__ idx1,
                                                       const __hip_bfloat16* __restrict__ wpk,
                                                       const float* __restrict__ bb,
                                                       const float* __restrict__ dw1,
                                                       const float* __restrict__ db1,
                                                       const float* __restrict__ dw2,
                                                       const float* __restrict__ db2,
                                                       float* __restrict__ pred) {
    __shared__ __hip_bfloat16 as[32][136];   // bf16 a-rows (2-way conflicts max)
    __shared__ float          bs[32][132];   // f32 b-rows
    __shared__ float          fl[ZDIM][32];  // elu(feat), transposed [k][p]
    const int p0  = blockIdx.x * 32;
    const int tid = threadIdx.x;

    for (int i = tid; i < 32 * 32; i += 512) {
        int p = i >> 5, q = i & 31;
        int pi = p0 + p; if (pi >= N_PAIRS) pi = N_PAIRS - 1;
        const float4 av = *reinterpret_cast<const float4*>(&latent[(long)idx0[pi] * 128 + q * 4]);
        const float4 bv = *reinterpret_cast<const float4*>(&latent[(long)idx1[pi] * 128 + q * 4]);
        as[p][q * 4 + 0] = __float2bfloat16(av.x);
        as[p][q * 4 + 1] = __float2bfloat16(av.y);
        as[p][q * 4 + 2] = __float2bfloat16(av.z);
        as[p][q * 4 + 3] = __float2bfloat16(av.w);
        *reinterpret_cast<float4*>(&bs[p][q * 4]) = bv;
    }
    __syncthreads();

    const int wave = tid >> 6;          // 0..7  -> k = 4*wave + k2
    const int lane = tid & 63;
    const int l15  = lane & 15, l4 = lane >> 4;

    // A fragments: af[M][kk], lane l holds A[M*16 + (l&15)][kk*32 + (l>>4)*8 + j]
    bf16x8 af[2][4];
#pragma unroll
    for (int M = 0; M < 2; ++M)
#pragma unroll
        for (int kk = 0; kk < 4; ++kk)
            af[M][kk] = *reinterpret_cast<const bf16x8*>(&as[M * 16 + l15][kk * 32 + l4 * 8]);

    float fsum[2][4][4];
#pragma unroll
    for (int M = 0; M < 2; ++M)
#pragma unroll
        for (int k2 = 0; k2 < 4; ++k2)
#pragma unroll
            for (int q = 0; q < 4; ++q) fsum[M][k2][q] = 0.f;

    for (int n = 0; n < 8; ++n) {
        float bval[2][4];   // b[M*16 + l4*4 + q][n*16 + l15]
#pragma unroll
        for (int M = 0; M < 2; ++M)
#pragma unroll
            for (int q = 0; q < 4; ++q)
                bval[M][q] = bs[M * 16 + l4 * 4 + q][n * 16 + l15];

#pragma unroll
        for (int k2 = 0; k2 < 4; ++k2) {
            const int k = wave * 4 + k2;
            f32x4 acc0 = {0.f, 0.f, 0.f, 0.f};
            f32x4 acc1 = {0.f, 0.f, 0.f, 0.f};
#pragma unroll
            for (int kk = 0; kk < 4; ++kk) {
                bf16x8 wf = *reinterpret_cast<const bf16x8*>(
                    &wpk[(((long)(k * 4 + kk) * 8 + n) * 512) + lane * 8]);
                acc0 = __builtin_amdgcn_mfma_f32_16x16x32_bf16(af[0][kk], wf, acc0, 0, 0, 0);
                acc1 = __builtin_amdgcn_mfma_f32_16x16x32_bf16(af[1][kk], wf, acc1, 0, 0, 0);
            }
#pragma unroll
            for (int q = 0; q < 4; ++q) {
                fsum[0][k2][q] += acc0[q] * bval[0][q];
                fsum[1][k2][q] += acc1[q] * bval[1][q];
            }
        }
    }

    // reduce over 16 e-lanes; lane l15==0 writes elu(feat) into fl[k][p]
#pragma unroll
    for (int M = 0; M < 2; ++M)
#pragma unroll
        for (int k2 = 0; k2 < 4; ++k2) {
            float v0 = fsum[M][k2][0], v1 = fsum[M][k2][1],
                  v2 = fsum[M][k2][2], v3 = fsum[M][k2][3];
#pragma unroll
            for (int off = 1; off < 16; off <<= 1) {
                v0 += __shfl_xor(v0, off);
                v1 += __shfl_xor(v1, off);
                v2 += __shfl_xor(v2, off);
                v3 += __shfl_xor(v3, off);
            }
            if (l15 == 0) {
                const int k = wave * 4 + k2;
                const float bbk = bb[k];
                float vv[4] = {v0, v1, v2, v3};
#pragma unroll
                for (int q = 0; q < 4; ++q) {
                    float v = vv[q] + bbk;
                    fl[k][M * 16 + l4 * 4 + q] = (v > 0.f) ? v : (expf(v) - 1.f);
                }
            }
        }
    __syncthreads();

    // fused MLP: thread t < 32 handles pair t. fl reads conflict-free (lane = p).
    if (tid < 32) {
        int p = p0 + tid;
        if (p < N_PAIRS) {
            float f[ZDIM];
#pragma unroll
            for (int k = 0; k < ZDIM; ++k) f[k] = fl[k][tid];
            float acc = db2[0];
            for (int j = 0; j < ZDIM; ++j) {
                float h = db1[j];
#pragma unroll
                for (int k = 0; k < ZDIM; ++k) h += f[k] * dw1[k * ZDIM + j];
                h = (h > 0.f) ? h : (expf(h) - 1.f);
                acc += h * dw2[j];
            }
            pred[p] = acc;
        }
    }
}

extern "C" void kernel_launch(void* const* d_in, const int* in_sizes, int n_in,
                              void* d_out, int out_size, void* d_ws, size_t ws_size,
                              hipStream_t stream) {
    const float* features = (const float*)d_in[0];
    const int*   adj_row  = (const int*)d_in[1];
    const int*   adj_col  = (const int*)d_in[2];
    const float* adj_val  = (const float*)d_in[3];
    const int*   idx      = (const int*)d_in[4];   // [2, N_PAIRS]
    const float* W0 = (const float*)d_in[5];
    const float* b0 = (const float*)d_in[6];
    const float* W1 = (const float*)d_in[7];
    const float* b1 = (const float*)d_in[8];
    const float* W2 = (const float*)d_in[9];
    const float* b2 = (const float*)d_in[10];
    const float* bil_w = (const float*)d_in[11];
    const float* bil_b = (const float*)d_in[12];
    const float* dw1 = (const float*)d_in[13];
    const float* db1 = (const float*)d_in[14];
    const float* dw2 = (const float*)d_in[15];
    const float* db2 = (const float*)d_in[16];

    float* pred   = (float*)d_out;                // [N_PAIRS]
    float* latent = (float*)d_out + N_PAIRS;      // [N_NODES,128]

    // workspace carve-up
    char* ws = (char*)d_ws;
    float* xw   = (float*)ws;                                 ws += (size_t)N_NODES * NHID * 4;
    float* xcur = (float*)ws;                                 ws += (size_t)N_NODES * NHID * 4;
    int*   row_ptr = (int*)ws;                                ws += (size_t)(N_NODES + 1) * 4;
    __hip_bfloat16* wpk = (__hip_bfloat16*)ws;                ws += (size_t)ZDIM * NHID * NHID * 2;

    const int*  idx0 = idx;
    const int*  idx1 = idx + N_PAIRS;

    k_build_row_ptr<<<(N_EDGES + 255) / 256, 256, 0, stream>>>(adj_row, row_ptr);
    k_pack_w<<<(ZDIM * NHID * NHID) / 256, 256, 0, stream>>>(bil_w, wpk);

    const int GB  = (N_NODES + 31) / 32;   // 1563 blocks
    const int SB  = (N_NODES + 7) / 8;     // 6250 blocks

    // layer 0
    k_gemm<NFEAT><<<GB, 256, 0, stream>>>(features, W0, xw);
    k_spmm_post<false><<<SB, 256, 0, stream>>>(xw, row_ptr, adj_col, adj_val, b0, nullptr, xcur);

    // layer 1 (in-place residual)
    k_gemm<NHID><<<GB, 256, 0, stream>>>(xcur, W1, xw);
    k_spmm_post<true><<<SB, 256, 0, stream>>>(xw, row_ptr, adj_col, adj_val, b1, xcur, xcur);

    // layer 2 -> latent in d_out
    k_gemm<NHID><<<GB, 256, 0, stream>>>(xcur, W2, xw);
    k_spmm_post<true><<<SB, 256, 0, stream>>>(xw, row_ptr, adj_col, adj_val, b2, xcur, latent);

    // decode (bilinear + fused MLP)
    k_bilinear_mfma<<<(N_PAIRS + 31) / 32, 512, 0, stream>>>(latent, idx0, idx1, wpk, bil_b,
                                                             dw1, db1, dw2, db2, pred);
}

// Round 7
// 496.554 us; speedup vs baseline: 2.2673x; 1.1344x over previous
//
#include <hip/hip_runtime.h>
#include <hip/hip_bf16.h>
#include <math.h>

#define N_NODES 50000
#define N_EDGES 800000
#define NFEAT   256
#define NHID    128
#define ZDIM    32
#define N_PAIRS 10000

typedef __attribute__((ext_vector_type(8))) short bf16x8;
typedef __attribute__((ext_vector_type(4))) float f32x4;

// ---------------- row_ptr build (adj_row is sorted ascending) ----------------
__global__ void k_build_row_ptr(const int* __restrict__ row, int* __restrict__ row_ptr) {
    int e = blockIdx.x * blockDim.x + threadIdx.x;
    if (e >= N_EDGES) return;
    int cur  = row[e];
    int prev = (e == 0) ? -1 : row[e - 1];
    for (int r = prev + 1; r <= cur; ++r) row_ptr[r] = e;
    if (e == N_EDGES - 1) {
        for (int r = cur + 1; r <= N_NODES; ++r) row_ptr[r] = N_EDGES;
    }
}

// ---------------- dense GEMM: Y[N,128] = X[N,K] @ W[K,128] (fp32) ----------------
template <int K>
__global__ __launch_bounds__(256) void k_gemm(const float* __restrict__ X,
                                              const float* __restrict__ W,
                                              float* __restrict__ Y) {
    const int ROWS = 32;
    __shared__ float xs[ROWS][K];
    const int tid = threadIdx.x;
    const long r0 = (long)blockIdx.x * ROWS;

    const float4* X4 = reinterpret_cast<const float4*>(X + r0 * K);
    float4* xs4 = reinterpret_cast<float4*>(&xs[0][0]);
    const int NV = ROWS * K / 4;
    for (int i = tid; i < NV; i += 256) {
        int row = i / (K / 4);
        float4 v = make_float4(0.f, 0.f, 0.f, 0.f);
        if (r0 + row < N_NODES) v = X4[i];
        xs4[i] = v;
    }
    __syncthreads();

    const int cp = tid & 63;
    const int rbase = (tid >> 6) * 8;

    float acc[8][2];
#pragma unroll
    for (int r = 0; r < 8; ++r) { acc[r][0] = 0.f; acc[r][1] = 0.f; }

    for (int k = 0; k < K; k += 4) {
        float2 w0 = *reinterpret_cast<const float2*>(&W[(k + 0) * 128 + 2 * cp]);
        float2 w1 = *reinterpret_cast<const float2*>(&W[(k + 1) * 128 + 2 * cp]);
        float2 w2 = *reinterpret_cast<const float2*>(&W[(k + 2) * 128 + 2 * cp]);
        float2 w3 = *reinterpret_cast<const float2*>(&W[(k + 3) * 128 + 2 * cp]);
#pragma unroll
        for (int r = 0; r < 8; ++r) {
            float4 a = *reinterpret_cast<const float4*>(&xs[rbase + r][k]);
            acc[r][0] += a.x * w0.x + a.y * w1.x + a.z * w2.x + a.w * w3.x;
            acc[r][1] += a.x * w0.y + a.y * w1.y + a.z * w2.y + a.w * w3.y;
        }
    }
#pragma unroll
    for (int r = 0; r < 8; ++r) {
        long row = r0 + rbase + r;
        if (row < N_NODES)
            *reinterpret_cast<float2*>(&Y[row * 128 + 2 * cp]) = make_float2(acc[r][0], acc[r][1]);
    }
}

// ---------------- spmm + bias + relu (+ residual), fused ----------------
// one wave (64 lanes) per destination node; lane owns 2 feats (float2).
// Edge metadata loaded coalesced in 64-chunks, broadcast via __shfl.
template <bool HAS_RES>
__global__ __launch_bounds__(256) void k_spmm_post(const float* __restrict__ H,
                                                   const int* __restrict__ row_ptr,
                                                   const int* __restrict__ col,
                                                   const float* __restrict__ val,
                                                   const float* __restrict__ bias,
                                                   const float* __restrict__ res,
                                                   float* __restrict__ out) {
    const int w    = threadIdx.x >> 6;          // wave in block (0..3)
    const int lane = threadIdx.x & 63;
    const int r    = blockIdx.x * 4 + w;
    if (r >= N_NODES) return;
    const int e0 = row_ptr[r], e1 = row_ptr[r + 1];
    const float2* H2 = reinterpret_cast<const float2*>(H);

    float2 acc = make_float2(0.f, 0.f);
    for (int base = e0; base < e1; base += 64) {
        int n = e1 - base; if (n > 64) n = 64;
        float v = 0.f; int c = 0;
        if (lane < n) { v = val[base + lane]; c = col[base + lane]; }
#pragma unroll 2
        for (int i = 0; i < n; ++i) {
            float vi = __shfl(v, i);
            int   ci = __shfl(c, i);
            float2 h = H2[(long)ci * 64 + lane];
            acc.x += vi * h.x;
            acc.y += vi * h.y;
        }
    }

    float2 bv = reinterpret_cast<const float2*>(bias)[lane];
    acc.x = fmaxf(acc.x + bv.x, 0.f);
    acc.y = fmaxf(acc.y + bv.y, 0.f);
    if (HAS_RES) {
        float2 rv = reinterpret_cast<const float2*>(res)[(long)r * 64 + lane];
        acc.x += rv.x; acc.y += rv.y;
    }
    reinterpret_cast<float2*>(out)[(long)r * 64 + lane] = acc;
}

// ---------------- pack bil_w into MFMA B-fragment order, f32 -> bf16 ----------
// chunk c = (k*4+kk)*8+n holds 512 bf16; element (lane,j) = W[k][kk*32+(l>>4)*8+j][n*16+(l&15)]
__global__ __launch_bounds__(256) void k_pack_w(const float* __restrict__ bw,
                                                __hip_bfloat16* __restrict__ wpk) {
    int i  = blockIdx.x * 256 + threadIdx.x;     // 0 .. 2^19-1
    int j  = i & 7;
    int l  = (i >> 3) & 63;
    int n  = (i >> 9) & 7;
    int kk = (i >> 12) & 3;
    int k  = i >> 14;
    int d  = kk * 32 + (l >> 4) * 8 + j;
    int e  = n * 16 + (l & 15);
    wpk[i] = __float2bfloat16(bw[((long)k * 128 + d) * 128 + e]);
}

// ---------------- bilinear decode via MFMA + fused MLP ----------------
// block = 512 threads (8 waves), 32 pairs. wave w owns k = 4w..4w+3, processed
// SEQUENTIALLY (k2 outer, no unroll) to keep ~85 live VGPRs -> no scratch.
__global__ __launch_bounds__(512, 4) void k_bilinear_mfma(const float* __restrict__ latent,
                                                          const int* __restrict__ idx0,
                                                          const int* __restrict__ idx1,
                                                          const __hip_bfloat16* __restrict__ wpk,
                                                          const float* __restrict__ bb,
                                                          const float* __restrict__ dw1,
                                                          const float* __restrict__ db1,
                                                          const float* __restrict__ dw2,
                                                          const float* __restrict__ db2,
                                                          float* __restrict__ pred) {
    __shared__ __hip_bfloat16 as[32][136];   // bf16 a-rows
    __shared__ float          bs[32][132];   // f32 b-rows
    __shared__ float          fl[ZDIM][32];  // elu(feat), transposed [k][p]
    const int p0  = blockIdx.x * 32;
    const int tid = threadIdx.x;

    for (int i = tid; i < 32 * 32; i += 512) {
        int p = i >> 5, q = i & 31;
        int pi = p0 + p; if (pi >= N_PAIRS) pi = N_PAIRS - 1;
        const float4 av = *reinterpret_cast<const float4*>(&latent[(long)idx0[pi] * 128 + q * 4]);
        const float4 bv = *reinterpret_cast<const float4*>(&latent[(long)idx1[pi] * 128 + q * 4]);
        as[p][q * 4 + 0] = __float2bfloat16(av.x);
        as[p][q * 4 + 1] = __float2bfloat16(av.y);
        as[p][q * 4 + 2] = __float2bfloat16(av.z);
        as[p][q * 4 + 3] = __float2bfloat16(av.w);
        *reinterpret_cast<float4*>(&bs[p][q * 4]) = bv;
    }
    __syncthreads();

    const int wave = tid >> 6;          // 0..7  -> k = 4*wave + k2
    const int lane = tid & 63;
    const int l15  = lane & 15, l4 = lane >> 4;

    // A fragments: af[M][kk], lane l holds A[M*16 + (l&15)][kk*32 + (l>>4)*8 + j]
    bf16x8 af[2][4];
#pragma unroll
    for (int M = 0; M < 2; ++M)
#pragma unroll
        for (int kk = 0; kk < 4; ++kk)
            af[M][kk] = *reinterpret_cast<const bf16x8*>(&as[M * 16 + l15][kk * 32 + l4 * 8]);

#pragma unroll 1
    for (int k2 = 0; k2 < 4; ++k2) {
        const int k = wave * 4 + k2;
        float fsum[2][4];
#pragma unroll
        for (int M = 0; M < 2; ++M)
#pragma unroll
            for (int q = 0; q < 4; ++q) fsum[M][q] = 0.f;

#pragma unroll 1
        for (int n = 0; n < 8; ++n) {
            f32x4 acc0 = {0.f, 0.f, 0.f, 0.f};
            f32x4 acc1 = {0.f, 0.f, 0.f, 0.f};
#pragma unroll
            for (int kk = 0; kk < 4; ++kk) {
                bf16x8 wf = *reinterpret_cast<const bf16x8*>(
                    &wpk[(((long)(k * 4 + kk) * 8 + n) * 512) + lane * 8]);
                acc0 = __builtin_amdgcn_mfma_f32_16x16x32_bf16(af[0][kk], wf, acc0, 0, 0, 0);
                acc1 = __builtin_amdgcn_mfma_f32_16x16x32_bf16(af[1][kk], wf, acc1, 0, 0, 0);
            }
#pragma unroll
            for (int q = 0; q < 4; ++q) {
                fsum[0][q] += acc0[q] * bs[l4 * 4 + q][n * 16 + l15];
                fsum[1][q] += acc1[q] * bs[16 + l4 * 4 + q][n * 16 + l15];
            }
        }

        // reduce over the 16 e-lanes; lane l15==0 writes elu(feat) into fl[k][p]
#pragma unroll
        for (int M = 0; M < 2; ++M) {
            float v0 = fsum[M][0], v1 = fsum[M][1], v2 = fsum[M][2], v3 = fsum[M][3];
#pragma unroll
            for (int off = 1; off < 16; off <<= 1) {
                v0 += __shfl_xor(v0, off);
                v1 += __shfl_xor(v1, off);
                v2 += __shfl_xor(v2, off);
                v3 += __shfl_xor(v3, off);
            }
            if (l15 == 0) {
                const float bbk = bb[k];
                float vv[4] = {v0, v1, v2, v3};
#pragma unroll
                for (int q = 0; q < 4; ++q) {
                    float v = vv[q] + bbk;
                    fl[k][M * 16 + l4 * 4 + q] = (v > 0.f) ? v : (expf(v) - 1.f);
                }
            }
        }
    }
    __syncthreads();

    // fused MLP: thread t < 32 handles pair t. fl reads conflict-free (lane = p).
    if (tid < 32) {
        int p = p0 + tid;
        if (p < N_PAIRS) {
            float f[ZDIM];
#pragma unroll
            for (int k = 0; k < ZDIM; ++k) f[k] = fl[k][tid];
            float acc = db2[0];
            for (int j = 0; j < ZDIM; ++j) {
                float h = db1[j];
#pragma unroll
                for (int k = 0; k < ZDIM; ++k) h += f[k] * dw1[k * ZDIM + j];
                h = (h > 0.f) ? h : (expf(h) - 1.f);
                acc += h * dw2[j];
            }
            pred[p] = acc;
        }
    }
}

extern "C" void kernel_launch(void* const* d_in, const int* in_sizes, int n_in,
                              void* d_out, int out_size, void* d_ws, size_t ws_size,
                              hipStream_t stream) {
    const float* features = (const float*)d_in[0];
    const int*   adj_row  = (const int*)d_in[1];
    const int*   adj_col  = (const int*)d_in[2];
    const float* adj_val  = (const float*)d_in[3];
    const int*   idx      = (const int*)d_in[4];   // [2, N_PAIRS]
    const float* W0 = (const float*)d_in[5];
    const float* b0 = (const float*)d_in[6];
    const float* W1 = (const float*)d_in[7];
    const float* b1 = (const float*)d_in[8];
    const float* W2 = (const float*)d_in[9];
    const float* b2 = (const float*)d_in[10];
    const float* bil_w = (const float*)d_in[11];
    const float* bil_b = (const float*)d_in[12];
    const float* dw1 = (const float*)d_in[13];
    const float* db1 = (const float*)d_in[14];
    const float* dw2 = (const float*)d_in[15];
    const float* db2 = (const float*)d_in[16];

    float* pred   = (float*)d_out;                // [N_PAIRS]
    float* latent = (float*)d_out + N_PAIRS;      // [N_NODES,128]

    // workspace carve-up
    char* ws = (char*)d_ws;
    float* xw   = (float*)ws;                                 ws += (size_t)N_NODES * NHID * 4;
    float* xcur = (float*)ws;                                 ws += (size_t)N_NODES * NHID * 4;
    int*   row_ptr = (int*)ws;                                ws += (size_t)(N_NODES + 1) * 4;
    __hip_bfloat16* wpk = (__hip_bfloat16*)ws;                ws += (size_t)ZDIM * NHID * NHID * 2;

    const int*  idx0 = idx;
    const int*  idx1 = idx + N_PAIRS;

    k_build_row_ptr<<<(N_EDGES + 255) / 256, 256, 0, stream>>>(adj_row, row_ptr);
    k_pack_w<<<(ZDIM * NHID * NHID) / 256, 256, 0, stream>>>(bil_w, wpk);

    const int GB  = (N_NODES + 31) / 32;   // 1563 blocks
    const int SB  = (N_NODES + 3) / 4;     // 12500 blocks (wave per node)

    // layer 0
    k_gemm<NFEAT><<<GB, 256, 0, stream>>>(features, W0, xw);
    k_spmm_post<false><<<SB, 256, 0, stream>>>(xw, row_ptr, adj_col, adj_val, b0, nullptr, xcur);

    // layer 1 (in-place residual)
    k_gemm<NHID><<<GB, 256, 0, stream>>>(xcur, W1, xw);
    k_spmm_post<true><<<SB, 256, 0, stream>>>(xw, row_ptr, adj_col, adj_val, b1, xcur, xcur);

    // layer 2 -> latent in d_out
    k_gemm<NHID><<<GB, 256, 0, stream>>>(xcur, W2, xw);
    k_spmm_post<true><<<SB, 256, 0, stream>>>(xw, row_ptr, adj_col, adj_val, b2, xcur, latent);

    // decode (bilinear + fused MLP)
    k_bilinear_mfma<<<(N_PAIRS + 31) / 32, 512, 0, stream>>>(latent, idx0, idx1, wpk, bil_b,
                                                             dw1, db1, dw2, db2, pred);
}

// Round 8
// 431.157 us; speedup vs baseline: 2.6112x; 1.1517x over previous
//
#include <hip/hip_runtime.h>
#include <hip/hip_bf16.h>
#include <math.h>

#define N_NODES 50000
#define N_EDGES 800000
#define NFEAT   256
#define NHID    128
#define ZDIM    32
#define N_PAIRS 10000

typedef __attribute__((ext_vector_type(8))) short bf16x8;
typedef __attribute__((ext_vector_type(4))) float f32x4;

// ---------------- row_ptr build (adj_row is sorted ascending) ----------------
__global__ void k_build_row_ptr(const int* __restrict__ row, int* __restrict__ row_ptr) {
    int e = blockIdx.x * blockDim.x + threadIdx.x;
    if (e >= N_EDGES) return;
    int cur  = row[e];
    int prev = (e == 0) ? -1 : row[e - 1];
    for (int r = prev + 1; r <= cur; ++r) row_ptr[r] = e;
    if (e == N_EDGES - 1) {
        for (int r = cur + 1; r <= N_NODES; ++r) row_ptr[r] = N_EDGES;
    }
}

// ---------------- pack a [K,128] f32 weight into MFMA B-frag order (bf16) ----
// linear i = ((kk*8 + n)*64 + l)*8 + j  ->  W[kk*32 + (l>>4)*8 + j][n*16 + (l&15)]
// (works for any K: kk = i>>12). Same layout validated by the bilinear kernel.
__global__ __launch_bounds__(256) void k_pack_gw(const float* __restrict__ W,
                                                 __hip_bfloat16* __restrict__ wpk) {
    int i  = blockIdx.x * 256 + threadIdx.x;
    int j  = i & 7;
    int l  = (i >> 3) & 63;
    int n  = (i >> 9) & 7;
    int kk = i >> 12;
    int d  = kk * 32 + (l >> 4) * 8 + j;
    int e  = n * 16 + (l & 15);
    wpk[i] = __float2bfloat16(W[(long)d * 128 + e]);
}

// ---------------- pack bil_w into B-frag order, SPLIT hi/lo bf16 ----------
__global__ __launch_bounds__(256) void k_pack_w2(const float* __restrict__ bw,
                                                 __hip_bfloat16* __restrict__ wh,
                                                 __hip_bfloat16* __restrict__ wl) {
    int i  = blockIdx.x * 256 + threadIdx.x;     // 0 .. 2^19-1
    int j  = i & 7;
    int l  = (i >> 3) & 63;
    int n  = (i >> 9) & 7;
    int kk = (i >> 12) & 3;
    int k  = i >> 14;
    int d  = kk * 32 + (l >> 4) * 8 + j;
    int e  = n * 16 + (l & 15);
    float w = bw[((long)k * 128 + d) * 128 + e];
    __hip_bfloat16 h = __float2bfloat16(w);
    wh[i] = h;
    wl[i] = __float2bfloat16(w - __bfloat162float(h));
}

// ---------------- dense GEMM via MFMA: Y[N,128] = X[N,K] @ W[K,128] ----------
// 256 threads = 4 waves; block = 64 rows; wave = 16 rows x 128 cols.
// X cast f32->bf16 into LDS; W from packed global (L2-resident, all-wave shared).
template <int K>
__global__ __launch_bounds__(256) void k_gemm_mfma(const float* __restrict__ X,
                                                   const __hip_bfloat16* __restrict__ wpk,
                                                   float* __restrict__ Y) {
    const int PAD = 8;
    __shared__ __hip_bfloat16 as[64][K + PAD];
    const int tid = threadIdx.x;
    const long r0 = (long)blockIdx.x * 64;

    const int QK = K / 4;
    for (int i = tid; i < 64 * QK; i += 256) {
        int row = i / QK, q = i - row * QK;
        float4 v = make_float4(0.f, 0.f, 0.f, 0.f);
        if (r0 + row < N_NODES)
            v = *reinterpret_cast<const float4*>(&X[(r0 + row) * (long)K + q * 4]);
        as[row][q * 4 + 0] = __float2bfloat16(v.x);
        as[row][q * 4 + 1] = __float2bfloat16(v.y);
        as[row][q * 4 + 2] = __float2bfloat16(v.z);
        as[row][q * 4 + 3] = __float2bfloat16(v.w);
    }
    __syncthreads();

    const int wrow = (tid >> 6) * 16;
    const int lane = tid & 63;
    const int l15  = lane & 15, l4 = lane >> 4;

    bf16x8 af[K / 32];
#pragma unroll
    for (int kk = 0; kk < K / 32; ++kk)
        af[kk] = *reinterpret_cast<const bf16x8*>(&as[wrow + l15][kk * 32 + l4 * 8]);

    f32x4 acc[8];
#pragma unroll
    for (int n = 0; n < 8; ++n) acc[n] = (f32x4){0.f, 0.f, 0.f, 0.f};

#pragma unroll 2
    for (int n = 0; n < 8; ++n) {
        f32x4 a = {0.f, 0.f, 0.f, 0.f};
#pragma unroll
        for (int kk = 0; kk < K / 32; ++kk) {
            bf16x8 wf = *reinterpret_cast<const bf16x8*>(&wpk[(((kk * 8 + n) * 64) + lane) * 8]);
            a = __builtin_amdgcn_mfma_f32_16x16x32_bf16(af[kk], wf, a, 0, 0, 0);
        }
        acc[n] = a;
    }

    // C/D layout: col = n*16 + (lane&15), row = wrow + (lane>>4)*4 + q
#pragma unroll
    for (int n = 0; n < 8; ++n)
#pragma unroll
        for (int q = 0; q < 4; ++q) {
            long row = r0 + wrow + l4 * 4 + q;
            if (row < N_NODES) Y[row * 128 + n * 16 + l15] = acc[n][q];
        }
}

// ---------------- spmm + bias + relu (+ residual), fused ----------------
// one wave (64 lanes) per destination node; lane owns 2 feats (float2).
template <bool HAS_RES>
__global__ __launch_bounds__(256) void k_spmm_post(const float* __restrict__ H,
                                                   const int* __restrict__ row_ptr,
                                                   const int* __restrict__ col,
                                                   const float* __restrict__ val,
                                                   const float* __restrict__ bias,
                                                   const float* __restrict__ res,
                                                   float* __restrict__ out) {
    const int w    = threadIdx.x >> 6;
    const int lane = threadIdx.x & 63;
    const int r    = blockIdx.x * 4 + w;
    if (r >= N_NODES) return;
    const int e0 = row_ptr[r], e1 = row_ptr[r + 1];
    const float2* H2 = reinterpret_cast<const float2*>(H);

    float2 acc = make_float2(0.f, 0.f);
    for (int base = e0; base < e1; base += 64) {
        int n = e1 - base; if (n > 64) n = 64;
        float v = 0.f; int c = 0;
        if (lane < n) { v = val[base + lane]; c = col[base + lane]; }
#pragma unroll 2
        for (int i = 0; i < n; ++i) {
            float vi = __shfl(v, i);
            int   ci = __shfl(c, i);
            float2 h = H2[(long)ci * 64 + lane];
            acc.x += vi * h.x;
            acc.y += vi * h.y;
        }
    }

    float2 bv = reinterpret_cast<const float2*>(bias)[lane];
    acc.x = fmaxf(acc.x + bv.x, 0.f);
    acc.y = fmaxf(acc.y + bv.y, 0.f);
    if (HAS_RES) {
        float2 rv = reinterpret_cast<const float2*>(res)[(long)r * 64 + lane];
        acc.x += rv.x; acc.y += rv.y;
    }
    reinterpret_cast<float2*>(out)[(long)r * 64 + lane] = acc;
}

// ---------------- bilinear decode via split-bf16 MFMA + fused MLP ----------------
// block = 512 threads (8 waves), 32 pairs. wave w owns k = 4w..4w+3 sequentially.
// a and W split hi/lo: acc = a_hi*W_hi + a_hi*W_lo + a_lo*W_hi (lo*lo dropped).
__global__ __launch_bounds__(512, 4) void k_bilinear_mfma(const float* __restrict__ latent,
                                                          const int* __restrict__ idx0,
                                                          const int* __restrict__ idx1,
                                                          const __hip_bfloat16* __restrict__ wpk_hi,
                                                          const __hip_bfloat16* __restrict__ wpk_lo,
                                                          const float* __restrict__ bb,
                                                          const float* __restrict__ dw1,
                                                          const float* __restrict__ db1,
                                                          const float* __restrict__ dw2,
                                                          const float* __restrict__ db2,
                                                          float* __restrict__ pred) {
    __shared__ __hip_bfloat16 ah[32][136];   // a hi
    __shared__ __hip_bfloat16 al[32][136];   // a lo
    __shared__ float          bs[32][132];   // f32 b-rows (exact contraction)
    __shared__ float          fl[ZDIM][32];  // elu(feat), transposed [k][p]
    const int p0  = blockIdx.x * 32;
    const int tid = threadIdx.x;

    for (int i = tid; i < 32 * 32; i += 512) {
        int p = i >> 5, q = i & 31;
        int pi = p0 + p; if (pi >= N_PAIRS) pi = N_PAIRS - 1;
        const float4 av = *reinterpret_cast<const float4*>(&latent[(long)idx0[pi] * 128 + q * 4]);
        const float4 bv = *reinterpret_cast<const float4*>(&latent[(long)idx1[pi] * 128 + q * 4]);
        float a4[4] = {av.x, av.y, av.z, av.w};
#pragma unroll
        for (int t = 0; t < 4; ++t) {
            __hip_bfloat16 h = __float2bfloat16(a4[t]);
            ah[p][q * 4 + t] = h;
            al[p][q * 4 + t] = __float2bfloat16(a4[t] - __bfloat162float(h));
        }
        *reinterpret_cast<float4*>(&bs[p][q * 4]) = bv;
    }
    __syncthreads();

    const int wave = tid >> 6;          // 0..7  -> k = 4*wave + k2
    const int lane = tid & 63;
    const int l15  = lane & 15, l4 = lane >> 4;

    // hoist hi A fragments only (32 VGPR); lo fragments re-read from LDS per use
    bf16x8 af[2][4];
#pragma unroll
    for (int M = 0; M < 2; ++M)
#pragma unroll
        for (int kk = 0; kk < 4; ++kk)
            af[M][kk] = *reinterpret_cast<const bf16x8*>(&ah[M * 16 + l15][kk * 32 + l4 * 8]);

#pragma unroll 1
    for (int k2 = 0; k2 < 4; ++k2) {
        const int k = wave * 4 + k2;
        float fsum[2][4];
#pragma unroll
        for (int M = 0; M < 2; ++M)
#pragma unroll
            for (int q = 0; q < 4; ++q) fsum[M][q] = 0.f;

#pragma unroll 1
        for (int n = 0; n < 8; ++n) {
            f32x4 acc0 = {0.f, 0.f, 0.f, 0.f};
            f32x4 acc1 = {0.f, 0.f, 0.f, 0.f};
#pragma unroll
            for (int kk = 0; kk < 4; ++kk) {
                const long ci = (((long)(k * 4 + kk) * 8 + n) * 512) + lane * 8;
                bf16x8 wh = *reinterpret_cast<const bf16x8*>(&wpk_hi[ci]);
                bf16x8 wl = *reinterpret_cast<const bf16x8*>(&wpk_lo[ci]);
                bf16x8 a0l = *reinterpret_cast<const bf16x8*>(&al[l15][kk * 32 + l4 * 8]);
                bf16x8 a1l = *reinterpret_cast<const bf16x8*>(&al[16 + l15][kk * 32 + l4 * 8]);
                acc0 = __builtin_amdgcn_mfma_f32_16x16x32_bf16(af[0][kk], wh, acc0, 0, 0, 0);
                acc0 = __builtin_amdgcn_mfma_f32_16x16x32_bf16(af[0][kk], wl, acc0, 0, 0, 0);
                acc0 = __builtin_amdgcn_mfma_f32_16x16x32_bf16(a0l,      wh, acc0, 0, 0, 0);
                acc1 = __builtin_amdgcn_mfma_f32_16x16x32_bf16(af[1][kk], wh, acc1, 0, 0, 0);
                acc1 = __builtin_amdgcn_mfma_f32_16x16x32_bf16(af[1][kk], wl, acc1, 0, 0, 0);
                acc1 = __builtin_amdgcn_mfma_f32_16x16x32_bf16(a1l,      wh, acc1, 0, 0, 0);
            }
#pragma unroll
            for (int q = 0; q < 4; ++q) {
                fsum[0][q] += acc0[q] * bs[l4 * 4 + q][n * 16 + l15];
                fsum[1][q] += acc1[q] * bs[16 + l4 * 4 + q][n * 16 + l15];
            }
        }

        // reduce over the 16 e-lanes; lane l15==0 writes elu(feat) into fl[k][p]
#pragma unroll
        for (int M = 0; M < 2; ++M) {
            float v0 = fsum[M][0], v1 = fsum[M][1], v2 = fsum[M][2], v3 = fsum[M][3];
#pragma unroll
            for (int off = 1; off < 16; off <<= 1) {
                v0 += __shfl_xor(v0, off);
                v1 += __shfl_xor(v1, off);
                v2 += __shfl_xor(v2, off);
                v3 += __shfl_xor(v3, off);
            }
            if (l15 == 0) {
                const float bbk = bb[k];
                float vv[4] = {v0, v1, v2, v3};
#pragma unroll
                for (int q = 0; q < 4; ++q) {
                    float v = vv[q] + bbk;
                    fl[k][M * 16 + l4 * 4 + q] = (v > 0.f) ? v : (expf(v) - 1.f);
                }
            }
        }
    }
    __syncthreads();

    // fused MLP: thread t < 32 handles pair t. fl reads conflict-free (lane = p).
    if (tid < 32) {
        int p = p0 + tid;
        if (p < N_PAIRS) {
            float f[ZDIM];
#pragma unroll
            for (int k = 0; k < ZDIM; ++k) f[k] = fl[k][tid];
            float acc = db2[0];
            for (int j = 0; j < ZDIM; ++j) {
                float h = db1[j];
#pragma unroll
                for (int k = 0; k < ZDIM; ++k) h += f[k] * dw1[k * ZDIM + j];
                h = (h > 0.f) ? h : (expf(h) - 1.f);
                acc += h * dw2[j];
            }
            pred[p] = acc;
        }
    }
}

extern "C" void kernel_launch(void* const* d_in, const int* in_sizes, int n_in,
                              void* d_out, int out_size, void* d_ws, size_t ws_size,
                              hipStream_t stream) {
    const float* features = (const float*)d_in[0];
    const int*   adj_row  = (const int*)d_in[1];
    const int*   adj_col  = (const int*)d_in[2];
    const float* adj_val  = (const float*)d_in[3];
    const int*   idx      = (const int*)d_in[4];   // [2, N_PAIRS]
    const float* W0 = (const float*)d_in[5];
    const float* b0 = (const float*)d_in[6];
    const float* W1 = (const float*)d_in[7];
    const float* b1 = (const float*)d_in[8];
    const float* W2 = (const float*)d_in[9];
    const float* b2 = (const float*)d_in[10];
    const float* bil_w = (const float*)d_in[11];
    const float* bil_b = (const float*)d_in[12];
    const float* dw1 = (const float*)d_in[13];
    const float* db1 = (const float*)d_in[14];
    const float* dw2 = (const float*)d_in[15];
    const float* db2 = (const float*)d_in[16];

    float* pred   = (float*)d_out;                // [N_PAIRS]
    float* latent = (float*)d_out + N_PAIRS;      // [N_NODES,128]

    // workspace carve-up
    char* ws = (char*)d_ws;
    float* xw   = (float*)ws;                                 ws += (size_t)N_NODES * NHID * 4;
    float* xcur = (float*)ws;                                 ws += (size_t)N_NODES * NHID * 4;
    int*   row_ptr = (int*)ws;                                ws += (size_t)(N_NODES + 1) * 4;
    __hip_bfloat16* wpk_hi = (__hip_bfloat16*)ws;             ws += (size_t)ZDIM * NHID * NHID * 2;
    __hip_bfloat16* wpk_lo = (__hip_bfloat16*)ws;             ws += (size_t)ZDIM * NHID * NHID * 2;
    __hip_bfloat16* w0pk = (__hip_bfloat16*)ws;               ws += (size_t)NFEAT * NHID * 2;
    __hip_bfloat16* w1pk = (__hip_bfloat16*)ws;               ws += (size_t)NHID * NHID * 2;
    __hip_bfloat16* w2pk = (__hip_bfloat16*)ws;               ws += (size_t)NHID * NHID * 2;

    const int*  idx0 = idx;
    const int*  idx1 = idx + N_PAIRS;

    k_build_row_ptr<<<(N_EDGES + 255) / 256, 256, 0, stream>>>(adj_row, row_ptr);
    k_pack_w2<<<(ZDIM * NHID * NHID) / 256, 256, 0, stream>>>(bil_w, wpk_hi, wpk_lo);
    k_pack_gw<<<(NFEAT * NHID) / 256, 256, 0, stream>>>(W0, w0pk);
    k_pack_gw<<<(NHID * NHID) / 256, 256, 0, stream>>>(W1, w1pk);
    k_pack_gw<<<(NHID * NHID) / 256, 256, 0, stream>>>(W2, w2pk);

    const int GB  = (N_NODES + 63) / 64;   // 782 blocks
    const int SB  = (N_NODES + 3) / 4;     // 12500 blocks (wave per node)

    // layer 0
    k_gemm_mfma<NFEAT><<<GB, 256, 0, stream>>>(features, w0pk, xw);
    k_spmm_post<false><<<SB, 256, 0, stream>>>(xw, row_ptr, adj_col, adj_val, b0, nullptr, xcur);

    // layer 1 (in-place residual)
    k_gemm_mfma<NHID><<<GB, 256, 0, stream>>>(xcur, w1pk, xw);
    k_spmm_post<true><<<SB, 256, 0, stream>>>(xw, row_ptr, adj_col, adj_val, b1, xcur, xcur);

    // layer 2 -> latent in d_out
    k_gemm_mfma<NHID><<<GB, 256, 0, stream>>>(xcur, w2pk, xw);
    k_spmm_post<true><<<SB, 256, 0, stream>>>(xw, row_ptr, adj_col, adj_val, b2, xcur, latent);

    // decode (bilinear + fused MLP)
    k_bilinear_mfma<<<(N_PAIRS + 31) / 32, 512, 0, stream>>>(latent, idx0, idx1, wpk_hi, wpk_lo,
                                                             bil_b, dw1, db1, dw2, db2, pred);
}